// Round 2
// baseline (1755.980 us; speedup 1.0000x reference)
//
#include <hip/hip_runtime.h>

#define N_NODES 100000
#define N_EDGES 3200000
#define R_REL   8
#define C_IN    128
#define HID     64
#define WCOLS   576   // 8 relations * 64 + 64 (root slot)

typedef __attribute__((ext_vector_type(8))) short  short8;
typedef __attribute__((ext_vector_type(4))) float  float4v;

__device__ __forceinline__ float bf2f(unsigned short u) {
    union { unsigned int i; float f; } v; v.i = ((unsigned int)u) << 16; return v.f;
}
__device__ __forceinline__ unsigned short f2bf(float f) {
    union { float f; unsigned int i; } v; v.f = f;
    unsigned int r = v.i + 0x7FFFu + ((v.i >> 16) & 1u);   // RNE
    return (unsigned short)(r >> 16);
}

// Build Wcat^T buffers (bf16): BT1[576][128], BT2[576][64] from f32 weights.
// col c<512: relation r=c>>6, out-channel h=c&63 ; col c>=512: root.
__global__ void prep_wcat(const float* __restrict__ W1,
                          const float* __restrict__ root1,
                          const float* __restrict__ W2,
                          const float* __restrict__ root2,
                          unsigned short* __restrict__ BT1,
                          unsigned short* __restrict__ BT2) {
    int idx = blockIdx.x * 256 + threadIdx.x;
    const int T1 = WCOLS * C_IN;          // 73728
    const int T2 = WCOLS * HID;           // 36864
    if (idx < T1) {
        int c = idx / C_IN, k = idx % C_IN;
        float v;
        if (c < 512) { int r = c >> 6, h = c & 63; v = W1[r * (C_IN * 64) + k * 64 + h]; }
        else         { v = root1[k * 64 + (c - 512)]; }
        BT1[idx] = f2bf(v);
    } else if (idx < T1 + T2) {
        int j = idx - T1;
        int c = j / HID, k = j % HID;
        float v;
        if (c < 512) { int r = c >> 6, h = c & 63; v = W2[r * (HID * 64) + k * 64 + h]; }
        else         { v = root2[k * 64 + (c - 512)]; }
        BT2[j] = f2bf(v);
    }
}

__global__ void deg_kernel(const int* __restrict__ dst, const int* __restrict__ et,
                           int* __restrict__ deg) {
    int e = blockIdx.x * 256 + threadIdx.x;
    if (e < N_EDGES) atomicAdd(&deg[et[e] * N_NODES + dst[e]], 1);
}

// Out[N][576] (bf16) = A[N][K] @ Wcat  (BT = Wcat^T, [576][K] bf16)
// AF32: A is f32 (converted to bf16 in-register); else A is bf16.
template <int K, bool AF32>
__global__ __launch_bounds__(256)
void gemm_rows(const void* __restrict__ Araw,
               const unsigned short* __restrict__ BT,
               unsigned short* __restrict__ Out, int nrows) {
    constexpr int KSTEPS = K / 32;
    constexpr int LDB = K + 8;                       // +16B pad: balanced banks
    __shared__ __align__(16) unsigned short Blds[64 * LDB];
    __shared__ __align__(16) unsigned short stage[4][16 * 64];

    const int wave = threadIdx.x >> 6;
    const int lane = threadIdx.x & 63;
    const int l15 = lane & 15, quad = lane >> 4;
    const int rowbase = blockIdx.x * 64 + wave * 16;
    int arow = rowbase + l15;
    if (arow >= nrows) arow = nrows - 1;             // clamp loads; stores guarded

    short8 afrag[KSTEPS];
    if constexpr (AF32) {
        const float* Af = (const float*)Araw;
#pragma unroll
        for (int ks = 0; ks < KSTEPS; ++ks) {
            const float* p = Af + (size_t)arow * K + ks * 32 + quad * 8;
            float4v u0 = *(const float4v*)p;
            float4v u1 = *(const float4v*)(p + 4);
            short8 f;
            f[0] = (short)f2bf(u0[0]); f[1] = (short)f2bf(u0[1]);
            f[2] = (short)f2bf(u0[2]); f[3] = (short)f2bf(u0[3]);
            f[4] = (short)f2bf(u1[0]); f[5] = (short)f2bf(u1[1]);
            f[6] = (short)f2bf(u1[2]); f[7] = (short)f2bf(u1[3]);
            afrag[ks] = f;
        }
    } else {
        const unsigned short* Ab = (const unsigned short*)Araw;
#pragma unroll
        for (int ks = 0; ks < KSTEPS; ++ks)
            afrag[ks] = *(const short8*)(Ab + (size_t)arow * K + ks * 32 + quad * 8);
    }

    for (int chunk = 0; chunk < 9; ++chunk) {
        __syncthreads();
        {   // stage 64 BT rows (contiguous 64*K bf16) into padded LDS
            const unsigned short* src = BT + (size_t)chunk * 64 * K;
            const int nvec = 64 * K / 8;
            for (int i = threadIdx.x; i < nvec; i += 256) {
                int r = i / (K / 8);
                int cpos = (i % (K / 8)) * 8;
                *(uint4*)(&Blds[r * LDB + cpos]) = *(const uint4*)(src + r * K + cpos);
            }
        }
        __syncthreads();

        float4v acc[4];
#pragma unroll
        for (int ct = 0; ct < 4; ++ct) { acc[ct][0] = 0.f; acc[ct][1] = 0.f; acc[ct][2] = 0.f; acc[ct][3] = 0.f; }

#pragma unroll
        for (int ct = 0; ct < 4; ++ct) {
#pragma unroll
            for (int ks = 0; ks < KSTEPS; ++ks) {
                short8 bfrag = *(const short8*)(&Blds[(ct * 16 + l15) * LDB + ks * 32 + quad * 8]);
                acc[ct] = __builtin_amdgcn_mfma_f32_16x16x32_bf16(afrag[ks], bfrag, acc[ct], 0, 0, 0);
            }
        }

        // D layout: col = lane&15, row = quad*4 + reg  -> stage tile, then coalesced store
#pragma unroll
        for (int ct = 0; ct < 4; ++ct)
#pragma unroll
            for (int r = 0; r < 4; ++r)
                stage[wave][(quad * 4 + r) * 64 + ct * 16 + l15] = f2bf(acc[ct][r]);
        __syncthreads();

        {
            int r = lane >> 2, j = lane & 3;
            int orow = rowbase + r;
            if (orow < nrows) {
#pragma unroll
                for (int p = 0; p < 2; ++p) {
                    int c0 = (j + p * 4) * 8;
                    uint4 v = *(const uint4*)&stage[wave][r * 64 + c0];
                    *(uint4*)(Out + (size_t)orow * WCOLS + chunk * 64 + c0) = v;
                }
            }
        }
    }
}

// agg[dst][c] += XW[src][et*64+c] / max(deg[et][dst],1), 64 lanes = one edge
__global__ __launch_bounds__(256)
void scatter_kernel(const unsigned short* __restrict__ XW,
                    const int* __restrict__ src, const int* __restrict__ dst,
                    const int* __restrict__ et, const int* __restrict__ deg,
                    float* __restrict__ agg) {
    long long tid = (long long)blockIdx.x * 256 + threadIdx.x;
    int e = (int)(tid >> 6), c = (int)(tid & 63);
    if (e >= N_EDGES) return;
    int s = src[e], d = dst[e], r = et[e];
    int dg = deg[r * N_NODES + d];
    float w = 1.0f / (float)(dg > 1 ? dg : 1);
    float v = bf2f(XW[(size_t)s * WCOLS + r * 64 + c]);
    atomicAdd(&agg[(size_t)d * 64 + c], v * w);
}

// v = agg + XW[:,512:576] + bias;  MODE 0: relu -> bf16 h ; MODE 1: -> f32 out
template <int MODE>
__global__ __launch_bounds__(256)
void combine_kernel(const float* __restrict__ agg, const unsigned short* __restrict__ XW,
                    const float* __restrict__ bias, void* __restrict__ outp) {
    int idx = blockIdx.x * 256 + threadIdx.x;   // N*64 threads
    int n = idx >> 6, c = idx & 63;
    float v = agg[idx] + bf2f(XW[(size_t)n * WCOLS + 512 + c]) + bias[c];
    if (MODE == 0) {
        v = v > 0.f ? v : 0.f;
        ((unsigned short*)outp)[idx] = f2bf(v);
    } else {
        ((float*)outp)[idx] = v;
    }
}

extern "C" void kernel_launch(void* const* d_in, const int* in_sizes, int n_in,
                              void* d_out, int out_size, void* d_ws, size_t ws_size,
                              hipStream_t stream) {
    const float* x     = (const float*)d_in[0];
    const int*   eidx  = (const int*)d_in[1];
    const int*   etyp  = (const int*)d_in[2];
    const float* W1    = (const float*)d_in[3];
    const float* root1 = (const float*)d_in[4];
    const float* b1    = (const float*)d_in[5];
    const float* W2    = (const float*)d_in[6];
    const float* root2 = (const float*)d_in[7];
    const float* b2    = (const float*)d_in[8];
    float*       out   = (float*)d_out;

    char* ws = (char*)d_ws;
    const size_t SZ_XW  = (size_t)N_NODES * WCOLS * 2;   // 115,200,000 (bf16; reused as hW)
    const size_t SZ_AGG = (size_t)N_NODES * 64 * 4;      //  25,600,000 (f32, reused)
    const size_t SZ_H   = (size_t)N_NODES * 64 * 2;      //  12,800,000 (bf16)
    const size_t SZ_DEG = (size_t)R_REL * N_NODES * 4;   //   3,200,000

    unsigned short* xW  = (unsigned short*)ws;
    float*          agg = (float*)(ws + SZ_XW);
    unsigned short* h   = (unsigned short*)(ws + SZ_XW + SZ_AGG);
    int*            deg = (int*)(ws + SZ_XW + SZ_AGG + SZ_H);
    unsigned short* BT1 = (unsigned short*)(ws + SZ_XW + SZ_AGG + SZ_H + SZ_DEG);
    unsigned short* BT2 = BT1 + WCOLS * C_IN;
    // total ws use: ~157.0 MB

    const int* srcp = eidx;
    const int* dstp = eidx + N_EDGES;

    hipMemsetAsync(deg, 0, SZ_DEG, stream);
    hipMemsetAsync(agg, 0, SZ_AGG, stream);

    prep_wcat<<<(WCOLS * (C_IN + HID) + 255) / 256, 256, 0, stream>>>(W1, root1, W2, root2, BT1, BT2);
    deg_kernel<<<(N_EDGES + 255) / 256, 256, 0, stream>>>(dstp, etyp, deg);

    const int gemm_grid = (N_NODES + 63) / 64;   // 1563
    const int scat_grid = (int)(((long long)N_EDGES * 64) / 256);   // 800000
    const int comb_grid = (N_NODES * 64) / 256;                     // 25000

    // layer 1: x (f32) -> xW (bf16) -> agg -> h (bf16, relu)
    gemm_rows<C_IN, true><<<gemm_grid, 256, 0, stream>>>((const void*)x, BT1, xW, N_NODES);
    scatter_kernel<<<scat_grid, 256, 0, stream>>>(xW, srcp, dstp, etyp, deg, agg);
    combine_kernel<0><<<comb_grid, 256, 0, stream>>>(agg, xW, b1, (void*)h);

    // layer 2: h (bf16) -> hW (reuse xW) -> agg -> out (f32)
    hipMemsetAsync(agg, 0, SZ_AGG, stream);
    gemm_rows<HID, false><<<gemm_grid, 256, 0, stream>>>((const void*)h, BT2, xW, N_NODES);
    scatter_kernel<<<scat_grid, 256, 0, stream>>>(xW, srcp, dstp, etyp, deg, agg);
    combine_kernel<1><<<comb_grid, 256, 0, stream>>>(agg, xW, b2, (void*)out);
}

// Round 3
// 913.800 us; speedup vs baseline: 1.9216x; 1.9216x over previous
//
#include <hip/hip_runtime.h>

#define N_NODES 100000
#define N_EDGES 3200000
#define R_REL   8
#define C_IN    128
#define HID     64
#define WCOLS   576   // 8 relations * 64 + 64 (root slot)

typedef __attribute__((ext_vector_type(8))) short  short8;
typedef __attribute__((ext_vector_type(4))) float  float4v;

__device__ __forceinline__ float bf2f(unsigned short u) {
    union { unsigned int i; float f; } v; v.i = ((unsigned int)u) << 16; return v.f;
}
__device__ __forceinline__ unsigned short f2bf(float f) {
    union { float f; unsigned int i; } v; v.f = f;
    unsigned int r = v.i + 0x7FFFu + ((v.i >> 16) & 1u);   // RNE
    return (unsigned short)(r >> 16);
}

// ---------------- weight prep (f32 -> bf16, concatenated+transposed) ----------
__global__ void prep_wcat(const float* __restrict__ W1,
                          const float* __restrict__ root1,
                          const float* __restrict__ W2,
                          const float* __restrict__ root2,
                          unsigned short* __restrict__ BT1,
                          unsigned short* __restrict__ BT2) {
    int idx = blockIdx.x * 256 + threadIdx.x;
    const int T1 = WCOLS * C_IN;          // 73728
    const int T2 = WCOLS * HID;           // 36864
    if (idx < T1) {
        int c = idx / C_IN, k = idx % C_IN;
        float v;
        if (c < 512) { int r = c >> 6, h = c & 63; v = W1[r * (C_IN * 64) + k * 64 + h]; }
        else         { v = root1[k * 64 + (c - 512)]; }
        BT1[idx] = f2bf(v);
    } else if (idx < T1 + T2) {
        int j = idx - T1;
        int c = j / HID, k = j % HID;
        float v;
        if (c < 512) { int r = c >> 6, h = c & 63; v = W2[r * (HID * 64) + k * 64 + h]; }
        else         { v = root2[k * 64 + (c - 512)]; }
        BT2[j] = f2bf(v);
    }
}

// ---------------- CSR build: histogram -> scan -> permute --------------------
__global__ void hist_kernel(const int* __restrict__ dst, int* __restrict__ cnt) {
    int e = blockIdx.x * 256 + threadIdx.x;
    if (e < N_EDGES) atomicAdd(&cnt[dst[e]], 1);
}

// block-level exclusive scan (1024/block); rowstart[i] = excl-within-block, bsum[b] = block total
__global__ __launch_bounds__(1024)
void scan_a(const int* __restrict__ cnt, int* __restrict__ rowstart, int* __restrict__ bsum) {
    __shared__ int tmp[1024];
    int tid = threadIdx.x;
    int gid = blockIdx.x * 1024 + tid;
    int v = (gid < N_NODES) ? cnt[gid] : 0;
    tmp[tid] = v; __syncthreads();
    for (int off = 1; off < 1024; off <<= 1) {
        int t = (tid >= off) ? tmp[tid - off] : 0;
        __syncthreads();
        tmp[tid] += t;
        __syncthreads();
    }
    int incl = tmp[tid];
    if (gid < N_NODES) rowstart[gid] = incl - v;
    if (tid == 1023) bsum[blockIdx.x] = incl;
}

__global__ void scan_b(int* __restrict__ bsum, int nb) {
    if (threadIdx.x == 0 && blockIdx.x == 0) {
        int run = 0;
        for (int i = 0; i < nb; ++i) { int t = bsum[i]; bsum[i] = run; run += t; }
    }
}

// rowstart[i] += bsum[block]; cursor[i] = rowstart[i]; rowstart[N] = E
__global__ __launch_bounds__(1024)
void scan_c(int* __restrict__ rowstart, const int* __restrict__ bsum, int* __restrict__ cursor) {
    int gid = blockIdx.x * 1024 + threadIdx.x;
    if (gid < N_NODES) {
        int v = rowstart[gid] + bsum[blockIdx.x];
        rowstart[gid] = v;
        cursor[gid] = v;
    }
    if (gid == 0) rowstart[N_NODES] = N_EDGES;
}

__global__ void permute_kernel(const int* __restrict__ src, const int* __restrict__ dst,
                               const int* __restrict__ et, int* __restrict__ cursor,
                               unsigned int* __restrict__ elist) {
    int e = blockIdx.x * 256 + threadIdx.x;
    if (e < N_EDGES) {
        int pos = atomicAdd(&cursor[dst[e]], 1);
        elist[pos] = (unsigned int)src[e] | ((unsigned int)et[e] << 20);
    }
}

// ---------------- GEMM: Out[N][576] (bf16) = A[N][K] @ Wcat ------------------
template <int K, bool AF32>
__global__ __launch_bounds__(256)
void gemm_rows(const void* __restrict__ Araw,
               const unsigned short* __restrict__ BT,
               unsigned short* __restrict__ Out, int nrows) {
    constexpr int KSTEPS = K / 32;
    constexpr int LDB = K + 8;
    __shared__ __align__(16) unsigned short Blds[64 * LDB];
    __shared__ __align__(16) unsigned short stage[4][16 * 64];

    const int wave = threadIdx.x >> 6;
    const int lane = threadIdx.x & 63;
    const int l15 = lane & 15, quad = lane >> 4;
    const int rowbase = blockIdx.x * 64 + wave * 16;
    int arow = rowbase + l15;
    if (arow >= nrows) arow = nrows - 1;

    short8 afrag[KSTEPS];
    if constexpr (AF32) {
        const float* Af = (const float*)Araw;
#pragma unroll
        for (int ks = 0; ks < KSTEPS; ++ks) {
            const float* p = Af + (size_t)arow * K + ks * 32 + quad * 8;
            float4v u0 = *(const float4v*)p;
            float4v u1 = *(const float4v*)(p + 4);
            short8 f;
            f[0] = (short)f2bf(u0[0]); f[1] = (short)f2bf(u0[1]);
            f[2] = (short)f2bf(u0[2]); f[3] = (short)f2bf(u0[3]);
            f[4] = (short)f2bf(u1[0]); f[5] = (short)f2bf(u1[1]);
            f[6] = (short)f2bf(u1[2]); f[7] = (short)f2bf(u1[3]);
            afrag[ks] = f;
        }
    } else {
        const unsigned short* Ab = (const unsigned short*)Araw;
#pragma unroll
        for (int ks = 0; ks < KSTEPS; ++ks)
            afrag[ks] = *(const short8*)(Ab + (size_t)arow * K + ks * 32 + quad * 8);
    }

    for (int chunk = 0; chunk < 9; ++chunk) {
        __syncthreads();
        {
            const unsigned short* src = BT + (size_t)chunk * 64 * K;
            const int nvec = 64 * K / 8;
            for (int i = threadIdx.x; i < nvec; i += 256) {
                int r = i / (K / 8);
                int cpos = (i % (K / 8)) * 8;
                *(uint4*)(&Blds[r * LDB + cpos]) = *(const uint4*)(src + r * K + cpos);
            }
        }
        __syncthreads();

        float4v acc[4];
#pragma unroll
        for (int ct = 0; ct < 4; ++ct) { acc[ct][0] = 0.f; acc[ct][1] = 0.f; acc[ct][2] = 0.f; acc[ct][3] = 0.f; }

#pragma unroll
        for (int ct = 0; ct < 4; ++ct) {
#pragma unroll
            for (int ks = 0; ks < KSTEPS; ++ks) {
                short8 bfrag = *(const short8*)(&Blds[(ct * 16 + l15) * LDB + ks * 32 + quad * 8]);
                acc[ct] = __builtin_amdgcn_mfma_f32_16x16x32_bf16(afrag[ks], bfrag, acc[ct], 0, 0, 0);
            }
        }

#pragma unroll
        for (int ct = 0; ct < 4; ++ct)
#pragma unroll
            for (int r = 0; r < 4; ++r)
                stage[wave][(quad * 4 + r) * 64 + ct * 16 + l15] = f2bf(acc[ct][r]);
        __syncthreads();

        {
            int r = lane >> 2, j = lane & 3;
            int orow = rowbase + r;
            if (orow < nrows) {
#pragma unroll
                for (int p = 0; p < 2; ++p) {
                    int c0 = (j + p * 4) * 8;
                    uint4 v = *(const uint4*)&stage[wave][r * 64 + c0];
                    *(uint4*)(Out + (size_t)orow * WCOLS + chunk * 64 + c0) = v;
                }
            }
        }
    }
}

// ---------------- fused CSR aggregate + root + bias (+relu) ------------------
// one wave per node, lane = out channel; per-relation mean via 8 acc/cnt regs
template <int MODE>   // 0: relu -> bf16 h ; 1: -> f32 out
__global__ __launch_bounds__(256)
void agg_fused(const unsigned short* __restrict__ XW,
               const unsigned int* __restrict__ elist,
               const int* __restrict__ rowstart,
               const float* __restrict__ bias,
               void* __restrict__ outp) {
    const int wave = threadIdx.x >> 6, lane = threadIdx.x & 63;
    const int n = blockIdx.x * 4 + wave;          // grid covers N exactly
    const int beg = rowstart[n], end = rowstart[n + 1];

    float a0=0.f,a1=0.f,a2=0.f,a3=0.f,a4=0.f,a5=0.f,a6=0.f,a7=0.f;
    int   c0=0,c1=0,c2=0,c3=0,c4=0,c5=0,c6=0,c7=0;

#define ACC(rr, vv) \
    { if ((rr)==0){a0+=(vv);c0++;} else if ((rr)==1){a1+=(vv);c1++;} \
      else if ((rr)==2){a2+=(vv);c2++;} else if ((rr)==3){a3+=(vv);c3++;} \
      else if ((rr)==4){a4+=(vv);c4++;} else if ((rr)==5){a5+=(vv);c5++;} \
      else if ((rr)==6){a6+=(vv);c6++;} else {a7+=(vv);c7++;} }

    int i = beg;
    for (; i + 1 < end; i += 2) {               // unroll-2: two gathers in flight
        int ua = __builtin_amdgcn_readfirstlane((int)elist[i]);
        int ub = __builtin_amdgcn_readfirstlane((int)elist[i + 1]);
        int ra = (ua >> 20) & 7, rb = (ub >> 20) & 7;
        int sa = ua & 0xFFFFF,  sb = ub & 0xFFFFF;
        float va = bf2f(XW[(size_t)sa * WCOLS + ra * 64 + lane]);
        float vb = bf2f(XW[(size_t)sb * WCOLS + rb * 64 + lane]);
        ACC(ra, va);
        ACC(rb, vb);
    }
    if (i < end) {
        int ua = __builtin_amdgcn_readfirstlane((int)elist[i]);
        int ra = (ua >> 20) & 7, sa = ua & 0xFFFFF;
        float va = bf2f(XW[(size_t)sa * WCOLS + ra * 64 + lane]);
        ACC(ra, va);
    }
#undef ACC

    float s = a0 / (float)(c0 > 1 ? c0 : 1) + a1 / (float)(c1 > 1 ? c1 : 1)
            + a2 / (float)(c2 > 1 ? c2 : 1) + a3 / (float)(c3 > 1 ? c3 : 1)
            + a4 / (float)(c4 > 1 ? c4 : 1) + a5 / (float)(c5 > 1 ? c5 : 1)
            + a6 / (float)(c6 > 1 ? c6 : 1) + a7 / (float)(c7 > 1 ? c7 : 1);

    float res = s + bf2f(XW[(size_t)n * WCOLS + 512 + lane]) + bias[lane];
    if (MODE == 0) {
        res = res > 0.f ? res : 0.f;
        ((unsigned short*)outp)[(size_t)n * 64 + lane] = f2bf(res);
    } else {
        ((float*)outp)[(size_t)n * 64 + lane] = res;
    }
}

// ---------------- launch ------------------------------------------------------
extern "C" void kernel_launch(void* const* d_in, const int* in_sizes, int n_in,
                              void* d_out, int out_size, void* d_ws, size_t ws_size,
                              hipStream_t stream) {
    const float* x     = (const float*)d_in[0];
    const int*   eidx  = (const int*)d_in[1];
    const int*   etyp  = (const int*)d_in[2];
    const float* W1    = (const float*)d_in[3];
    const float* root1 = (const float*)d_in[4];
    const float* b1    = (const float*)d_in[5];
    const float* W2    = (const float*)d_in[6];
    const float* root2 = (const float*)d_in[7];
    const float* b2    = (const float*)d_in[8];
    float*       out   = (float*)d_out;

    char* ws = (char*)d_ws;
    size_t off = 0;
    auto alloc = [&](size_t bytes) { char* p = ws + off; off += (bytes + 255) & ~(size_t)255; return p; };

    unsigned short* xW       = (unsigned short*)alloc((size_t)N_NODES * WCOLS * 2);  // 115.2 MB (reused as hW)
    unsigned short* h        = (unsigned short*)alloc((size_t)N_NODES * HID * 2);    //  12.8 MB
    unsigned int*   elist    = (unsigned int*)alloc((size_t)N_EDGES * 4);            //  12.8 MB
    int*            rowstart = (int*)alloc((size_t)(N_NODES + 1) * 4);
    int*            cnt_cur  = (int*)alloc((size_t)N_NODES * 4);                     // hist cnt, then cursor
    int*            bsum     = (int*)alloc(128 * 4);
    unsigned short* BT1      = (unsigned short*)alloc((size_t)WCOLS * C_IN * 2);
    unsigned short* BT2      = (unsigned short*)alloc((size_t)WCOLS * HID * 2);
    // total ~141.5 MB

    const int* srcp = eidx;
    const int* dstp = eidx + N_EDGES;

    const int NB_SCAN = (N_NODES + 1023) / 1024;   // 98
    const int eg = (N_EDGES + 255) / 256;          // 12500

    hipMemsetAsync(cnt_cur, 0, (size_t)N_NODES * 4, stream);
    prep_wcat<<<(WCOLS * (C_IN + HID) + 255) / 256, 256, 0, stream>>>(W1, root1, W2, root2, BT1, BT2);

    // CSR build (shared by both layers)
    hist_kernel<<<eg, 256, 0, stream>>>(dstp, cnt_cur);
    scan_a<<<NB_SCAN, 1024, 0, stream>>>(cnt_cur, rowstart, bsum);
    scan_b<<<1, 64, 0, stream>>>(bsum, NB_SCAN);
    scan_c<<<NB_SCAN, 1024, 0, stream>>>(rowstart, bsum, cnt_cur);
    permute_kernel<<<eg, 256, 0, stream>>>(srcp, dstp, etyp, cnt_cur, elist);

    const int gemm_grid = (N_NODES + 63) / 64;     // 1563
    const int agg_grid  = N_NODES / 4;             // 25000

    // layer 1: x (f32) -> xW (bf16) -> h (bf16, relu)
    gemm_rows<C_IN, true><<<gemm_grid, 256, 0, stream>>>((const void*)x, BT1, xW, N_NODES);
    agg_fused<0><<<agg_grid, 256, 0, stream>>>(xW, elist, rowstart, b1, (void*)h);

    // layer 2: h -> hW (reuse xW) -> out (f32)
    gemm_rows<HID, false><<<gemm_grid, 256, 0, stream>>>((const void*)h, BT2, xW, N_NODES);
    agg_fused<1><<<agg_grid, 256, 0, stream>>>(xW, elist, rowstart, b2, (void*)out);
}

// Round 4
// 906.276 us; speedup vs baseline: 1.9376x; 1.0083x over previous
//
#include <hip/hip_runtime.h>

#define N_NODES 100000
#define N_EDGES 3200000
#define R_REL   8
#define C_IN    128
#define HID     64
#define WCOLS   576   // 8 relations * 64 + 64 (root slot)
#define OFFMASK 0x03FFFFFFu

typedef __attribute__((ext_vector_type(8))) short  short8;
typedef __attribute__((ext_vector_type(4))) float  float4v;

__device__ __forceinline__ float bf2f(unsigned short u) {
    union { unsigned int i; float f; } v; v.i = ((unsigned int)u) << 16; return v.f;
}
__device__ __forceinline__ float bf2f_u32(unsigned int u) {   // low 16 bits = bf16
    union { unsigned int i; float f; } v; v.i = u << 16; return v.f;
}
__device__ __forceinline__ unsigned short f2bf(float f) {
    union { float f; unsigned int i; } v; v.f = f;
    unsigned int r = v.i + 0x7FFFu + ((v.i >> 16) & 1u);   // RNE
    return (unsigned short)(r >> 16);
}

// ---------------- weight prep (f32 -> bf16, concatenated+transposed) ----------
__global__ void prep_wcat(const float* __restrict__ W1,
                          const float* __restrict__ root1,
                          const float* __restrict__ W2,
                          const float* __restrict__ root2,
                          unsigned short* __restrict__ BT1,
                          unsigned short* __restrict__ BT2) {
    int idx = blockIdx.x * 256 + threadIdx.x;
    const int T1 = WCOLS * C_IN;          // 73728
    const int T2 = WCOLS * HID;           // 36864
    if (idx < T1) {
        int c = idx / C_IN, k = idx % C_IN;
        float v;
        if (c < 512) { int r = c >> 6, h = c & 63; v = W1[r * (C_IN * 64) + k * 64 + h]; }
        else         { v = root1[k * 64 + (c - 512)]; }
        BT1[idx] = f2bf(v);
    } else if (idx < T1 + T2) {
        int j = idx - T1;
        int c = j / HID, k = j % HID;
        float v;
        if (c < 512) { int r = c >> 6, h = c & 63; v = W2[r * (HID * 64) + k * 64 + h]; }
        else         { v = root2[k * 64 + (c - 512)]; }
        BT2[j] = f2bf(v);
    }
}

// ---------------- per-(rel,dst) degree + CSR build ---------------------------
__global__ void hist2_kernel(const int* __restrict__ dst, const int* __restrict__ et,
                             int* __restrict__ cnt2) {
    int e = blockIdx.x * 256 + threadIdx.x;
    if (e < N_EDGES) atomicAdd(&cnt2[et[e] * N_NODES + dst[e]], 1);
}

__global__ void recip_kernel(const int* __restrict__ cnt2, float* __restrict__ rdeg) {
    int i = blockIdx.x * 256 + threadIdx.x;
    if (i < R_REL * N_NODES) {
        int c = cnt2[i];
        rdeg[i] = 1.0f / (float)(c > 1 ? c : 1);
    }
}

// block-level exclusive scan over per-node totals (sum of 8 relation counts)
__global__ __launch_bounds__(1024)
void scan_a(const int* __restrict__ cnt2, int* __restrict__ rowstart, int* __restrict__ bsum) {
    __shared__ int tmp[1024];
    int tid = threadIdx.x;
    int gid = blockIdx.x * 1024 + tid;
    int v = 0;
    if (gid < N_NODES) {
#pragma unroll
        for (int r = 0; r < R_REL; ++r) v += cnt2[r * N_NODES + gid];
    }
    tmp[tid] = v; __syncthreads();
    for (int off = 1; off < 1024; off <<= 1) {
        int t = (tid >= off) ? tmp[tid - off] : 0;
        __syncthreads();
        tmp[tid] += t;
        __syncthreads();
    }
    int incl = tmp[tid];
    if (gid < N_NODES) rowstart[gid] = incl - v;
    if (tid == 1023) bsum[blockIdx.x] = incl;
}

__global__ void scan_b(int* __restrict__ bsum, int nb) {
    if (threadIdx.x == 0 && blockIdx.x == 0) {
        int run = 0;
        for (int i = 0; i < nb; ++i) { int t = bsum[i]; bsum[i] = run; run += t; }
    }
}

__global__ __launch_bounds__(1024)
void scan_c(int* __restrict__ rowstart, const int* __restrict__ bsum, int* __restrict__ cursor) {
    int gid = blockIdx.x * 1024 + threadIdx.x;
    if (gid < N_NODES) {
        int v = rowstart[gid] + bsum[blockIdx.x];
        rowstart[gid] = v;
        cursor[gid] = v;
    }
    if (gid == 0) rowstart[N_NODES] = N_EDGES;
}

// dst-range-binned permute: elist entry = (src*576 + rel*64) | (rel<<26)
__global__ void permute_binned(const int* __restrict__ src, const int* __restrict__ dst,
                               const int* __restrict__ et, int* __restrict__ cursor,
                               unsigned int* __restrict__ elist, int lo, int hi) {
    int e = blockIdx.x * 256 + threadIdx.x;
    if (e < N_EDGES) {
        int d = dst[e];
        if (d >= lo && d < hi) {
            int r = et[e];
            int pos = atomicAdd(&cursor[d], 1);
            elist[pos] = (unsigned int)(src[e] * WCOLS + r * 64) | ((unsigned int)r << 26);
        }
    }
}

// ---------------- GEMM: Out[N][576] (bf16) = A[N][K] @ Wcat ------------------
template <int K, bool AF32>
__global__ __launch_bounds__(256)
void gemm_rows(const void* __restrict__ Araw,
               const unsigned short* __restrict__ BT,
               unsigned short* __restrict__ Out, int nrows) {
    constexpr int KSTEPS = K / 32;
    constexpr int LDB = K + 8;
    __shared__ __align__(16) unsigned short Blds[64 * LDB];
    __shared__ __align__(16) unsigned short stage[4][16 * 64];

    const int wave = threadIdx.x >> 6;
    const int lane = threadIdx.x & 63;
    const int l15 = lane & 15, quad = lane >> 4;
    const int rowbase = blockIdx.x * 64 + wave * 16;
    int arow = rowbase + l15;
    if (arow >= nrows) arow = nrows - 1;

    short8 afrag[KSTEPS];
    if constexpr (AF32) {
        const float* Af = (const float*)Araw;
#pragma unroll
        for (int ks = 0; ks < KSTEPS; ++ks) {
            const float* p = Af + (size_t)arow * K + ks * 32 + quad * 8;
            float4v u0 = *(const float4v*)p;
            float4v u1 = *(const float4v*)(p + 4);
            short8 f;
            f[0] = (short)f2bf(u0[0]); f[1] = (short)f2bf(u0[1]);
            f[2] = (short)f2bf(u0[2]); f[3] = (short)f2bf(u0[3]);
            f[4] = (short)f2bf(u1[0]); f[5] = (short)f2bf(u1[1]);
            f[6] = (short)f2bf(u1[2]); f[7] = (short)f2bf(u1[3]);
            afrag[ks] = f;
        }
    } else {
        const unsigned short* Ab = (const unsigned short*)Araw;
#pragma unroll
        for (int ks = 0; ks < KSTEPS; ++ks)
            afrag[ks] = *(const short8*)(Ab + (size_t)arow * K + ks * 32 + quad * 8);
    }

    for (int chunk = 0; chunk < 9; ++chunk) {
        __syncthreads();
        {
            const unsigned short* src = BT + (size_t)chunk * 64 * K;
            const int nvec = 64 * K / 8;
            for (int i = threadIdx.x; i < nvec; i += 256) {
                int r = i / (K / 8);
                int cpos = (i % (K / 8)) * 8;
                *(uint4*)(&Blds[r * LDB + cpos]) = *(const uint4*)(src + r * K + cpos);
            }
        }
        __syncthreads();

        float4v acc[4];
#pragma unroll
        for (int ct = 0; ct < 4; ++ct) { acc[ct][0] = 0.f; acc[ct][1] = 0.f; acc[ct][2] = 0.f; acc[ct][3] = 0.f; }

#pragma unroll
        for (int ct = 0; ct < 4; ++ct) {
#pragma unroll
            for (int ks = 0; ks < KSTEPS; ++ks) {
                short8 bfrag = *(const short8*)(&Blds[(ct * 16 + l15) * LDB + ks * 32 + quad * 8]);
                acc[ct] = __builtin_amdgcn_mfma_f32_16x16x32_bf16(afrag[ks], bfrag, acc[ct], 0, 0, 0);
            }
        }

#pragma unroll
        for (int ct = 0; ct < 4; ++ct)
#pragma unroll
            for (int r = 0; r < 4; ++r)
                stage[wave][(quad * 4 + r) * 64 + ct * 16 + l15] = f2bf(acc[ct][r]);
        __syncthreads();

        {
            int r = lane >> 2, j = lane & 3;
            int orow = rowbase + r;
            if (orow < nrows) {
#pragma unroll
                for (int p = 0; p < 2; ++p) {
                    int c0 = (j + p * 4) * 8;
                    uint4 v = *(const uint4*)&stage[wave][r * 64 + c0];
                    *(uint4*)(Out + (size_t)orow * WCOLS + chunk * 64 + c0) = v;
                }
            }
        }
    }
}

// ---------------- fused CSR aggregate + root + bias (+relu) ------------------
// one wave per node, lane = channel; weighted sum (mean folded into per-edge w)
template <int MODE>   // 0: relu -> bf16 h ; 1: -> f32 out
__global__ __launch_bounds__(256)
void agg_fused(const unsigned short* __restrict__ XW,
               const unsigned int* __restrict__ elist,
               const int* __restrict__ rowstart,
               const float* __restrict__ rdeg,
               const float* __restrict__ bias,
               void* __restrict__ outp) {
    const int wave = threadIdx.x >> 6, lane = threadIdx.x & 63;
    const int n = blockIdx.x * 4 + wave;          // grid covers N exactly
    const int ns = __builtin_amdgcn_readfirstlane(n);

    const int beg = __builtin_amdgcn_readfirstlane(rowstart[ns]);
    const int end = __builtin_amdgcn_readfirstlane(rowstart[ns + 1]);
    const int len = end - beg;

    // 8 per-relation reciprocal degrees for this node (scalar regs)
    const float* rg = rdeg + ns;
    float w0 = rg[0 * N_NODES], w1 = rg[1 * N_NODES], w2 = rg[2 * N_NODES], w3 = rg[3 * N_NODES];
    float w4 = rg[4 * N_NODES], w5 = rg[5 * N_NODES], w6 = rg[6 * N_NODES], w7 = rg[7 * N_NODES];

    float acc = 0.f;
    for (int base = 0; base < len; base += 64) {
        int m = len - base; if (m > 64) m = 64;
        int idx = beg + base + lane;
        if (idx > N_EDGES - 1) idx = N_EDGES - 1;
        unsigned int ub = elist[idx];             // 64 entries, one coalesced load
#pragma unroll 4
        for (int j = 0; j < m; ++j) {
            unsigned int u = (unsigned int)__builtin_amdgcn_readlane((int)ub, j);
            int r = (int)(u >> 26);
            int off = (int)(u & OFFMASK);
            float w = (r == 0) ? w0 : (r == 1) ? w1 : (r == 2) ? w2 : (r == 3) ? w3
                    : (r == 4) ? w4 : (r == 5) ? w5 : (r == 6) ? w6 : w7;
            acc += w * bf2f(XW[off + lane]);
        }
    }

    float res = acc + bf2f(XW[(size_t)n * WCOLS + 512 + lane]) + bias[lane];
    if (MODE == 0) {
        res = res > 0.f ? res : 0.f;
        ((unsigned short*)outp)[(size_t)n * 64 + lane] = f2bf(res);
    } else {
        ((float*)outp)[(size_t)n * 64 + lane] = res;
    }
}

// ---------------- launch ------------------------------------------------------
extern "C" void kernel_launch(void* const* d_in, const int* in_sizes, int n_in,
                              void* d_out, int out_size, void* d_ws, size_t ws_size,
                              hipStream_t stream) {
    const float* x     = (const float*)d_in[0];
    const int*   eidx  = (const int*)d_in[1];
    const int*   etyp  = (const int*)d_in[2];
    const float* W1    = (const float*)d_in[3];
    const float* root1 = (const float*)d_in[4];
    const float* b1    = (const float*)d_in[5];
    const float* W2    = (const float*)d_in[6];
    const float* root2 = (const float*)d_in[7];
    const float* b2    = (const float*)d_in[8];
    float*       out   = (float*)d_out;

    char* ws = (char*)d_ws;
    size_t off = 0;
    auto alloc = [&](size_t bytes) { char* p = ws + off; off += (bytes + 255) & ~(size_t)255; return p; };

    unsigned short* xW       = (unsigned short*)alloc((size_t)N_NODES * WCOLS * 2);  // 115.2 MB (reused as hW)
    unsigned short* h        = (unsigned short*)alloc((size_t)N_NODES * HID * 2);    //  12.8 MB
    unsigned int*   elist    = (unsigned int*)alloc((size_t)N_EDGES * 4);            //  12.8 MB
    int*            rowstart = (int*)alloc((size_t)(N_NODES + 1) * 4);
    int*            cnt2     = (int*)alloc((size_t)R_REL * N_NODES * 4);             //   3.2 MB
    float*          rdeg     = (float*)alloc((size_t)R_REL * N_NODES * 4);           //   3.2 MB
    int*            cursor   = (int*)alloc((size_t)N_NODES * 4);
    int*            bsum     = (int*)alloc(128 * 4);
    unsigned short* BT1      = (unsigned short*)alloc((size_t)WCOLS * C_IN * 2);
    unsigned short* BT2      = (unsigned short*)alloc((size_t)WCOLS * HID * 2);
    // total ~148.3 MB

    const int* srcp = eidx;
    const int* dstp = eidx + N_EDGES;

    const int NB_SCAN = (N_NODES + 1023) / 1024;   // 98
    const int eg = (N_EDGES + 255) / 256;          // 12500

    hipMemsetAsync(cnt2, 0, (size_t)R_REL * N_NODES * 4, stream);
    prep_wcat<<<(WCOLS * (C_IN + HID) + 255) / 256, 256, 0, stream>>>(W1, root1, W2, root2, BT1, BT2);

    // CSR build (shared by both layers)
    hist2_kernel<<<eg, 256, 0, stream>>>(dstp, etyp, cnt2);
    recip_kernel<<<(R_REL * N_NODES + 255) / 256, 256, 0, stream>>>(cnt2, rdeg);
    scan_a<<<NB_SCAN, 1024, 0, stream>>>(cnt2, rowstart, bsum);
    scan_b<<<1, 64, 0, stream>>>(bsum, NB_SCAN);
    scan_c<<<NB_SCAN, 1024, 0, stream>>>(rowstart, bsum, cursor);
    // 4 dst-range passes: each writes a ~3.2 MB elist window (L2-resident)
    for (int p = 0; p < 4; ++p)
        permute_binned<<<eg, 256, 0, stream>>>(srcp, dstp, etyp, cursor, elist,
                                               p * (N_NODES / 4), (p + 1) * (N_NODES / 4));

    const int gemm_grid = (N_NODES + 63) / 64;     // 1563
    const int agg_grid  = N_NODES / 4;             // 25000

    // layer 1: x (f32) -> xW (bf16) -> h (bf16, relu)
    gemm_rows<C_IN, true><<<gemm_grid, 256, 0, stream>>>((const void*)x, BT1, xW, N_NODES);
    agg_fused<0><<<agg_grid, 256, 0, stream>>>(xW, elist, rowstart, rdeg, b1, (void*)h);

    // layer 2: h -> hW (reuse xW) -> out (f32)
    gemm_rows<HID, false><<<gemm_grid, 256, 0, stream>>>((const void*)h, BT2, xW, N_NODES);
    agg_fused<1><<<agg_grid, 256, 0, stream>>>(xW, elist, rowstart, rdeg, b2, (void*)out);
}

// Round 5
// 667.206 us; speedup vs baseline: 2.6318x; 1.3583x over previous
//
#include <hip/hip_runtime.h>

#define N_NODES 100000
#define N_EDGES 3200000
#define R_REL   8
#define C_IN    128
#define HID     64
#define WCOLS   576   // 8 relations * 64 + 64 (root slot)
#define OFFMASK 0x03FFFFFFu

typedef __attribute__((ext_vector_type(8))) short  short8;
typedef __attribute__((ext_vector_type(4))) float  float4v;

__device__ __forceinline__ float bf2f(unsigned short u) {
    union { unsigned int i; float f; } v; v.i = ((unsigned int)u) << 16; return v.f;
}
__device__ __forceinline__ unsigned short f2bf(float f) {
    union { float f; unsigned int i; } v; v.f = f;
    unsigned int r = v.i + 0x7FFFu + ((v.i >> 16) & 1u);   // RNE
    return (unsigned short)(r >> 16);
}
__device__ __forceinline__ float rl_f(float v, int j) {
    union { float f; int i; } a, b; a.f = v;
    b.i = __builtin_amdgcn_readlane(a.i, j);
    return b.f;
}

// ---------------- weight prep (f32 -> bf16, concatenated+transposed) ----------
__global__ void prep_wcat(const float* __restrict__ W1,
                          const float* __restrict__ root1,
                          const float* __restrict__ W2,
                          const float* __restrict__ root2,
                          unsigned short* __restrict__ BT1,
                          unsigned short* __restrict__ BT2) {
    int idx = blockIdx.x * 256 + threadIdx.x;
    const int T1 = WCOLS * C_IN;          // 73728
    const int T2 = WCOLS * HID;           // 36864
    if (idx < T1) {
        int c = idx / C_IN, k = idx % C_IN;
        float v;
        if (c < 512) { int r = c >> 6, h = c & 63; v = W1[r * (C_IN * 64) + k * 64 + h]; }
        else         { v = root1[k * 64 + (c - 512)]; }
        BT1[idx] = f2bf(v);
    } else if (idx < T1 + T2) {
        int j = idx - T1;
        int c = j / HID, k = j % HID;
        float v;
        if (c < 512) { int r = c >> 6, h = c & 63; v = W2[r * (HID * 64) + k * 64 + h]; }
        else         { v = root2[k * 64 + (c - 512)]; }
        BT2[j] = f2bf(v);
    }
}

// ---------------- per-(rel,dst) degree + CSR build ---------------------------
__global__ void hist2_kernel(const int* __restrict__ dst, const int* __restrict__ et,
                             int* __restrict__ cnt2) {
    int e = blockIdx.x * 256 + threadIdx.x;
    if (e < N_EDGES) atomicAdd(&cnt2[et[e] * N_NODES + dst[e]], 1);
}

__global__ void recip_kernel(const int* __restrict__ cnt2, float* __restrict__ rdeg) {
    int i = blockIdx.x * 256 + threadIdx.x;
    if (i < R_REL * N_NODES) {
        int c = cnt2[i];
        rdeg[i] = 1.0f / (float)(c > 1 ? c : 1);
    }
}

__global__ __launch_bounds__(1024)
void scan_a(const int* __restrict__ cnt2, int* __restrict__ rowstart, int* __restrict__ bsum) {
    __shared__ int tmp[1024];
    int tid = threadIdx.x;
    int gid = blockIdx.x * 1024 + tid;
    int v = 0;
    if (gid < N_NODES) {
#pragma unroll
        for (int r = 0; r < R_REL; ++r) v += cnt2[r * N_NODES + gid];
    }
    tmp[tid] = v; __syncthreads();
    for (int off = 1; off < 1024; off <<= 1) {
        int t = (tid >= off) ? tmp[tid - off] : 0;
        __syncthreads();
        tmp[tid] += t;
        __syncthreads();
    }
    int incl = tmp[tid];
    if (gid < N_NODES) rowstart[gid] = incl - v;
    if (tid == 1023) bsum[blockIdx.x] = incl;
}

__global__ void scan_b(int* __restrict__ bsum, int nb) {
    if (threadIdx.x == 0 && blockIdx.x == 0) {
        int run = 0;
        for (int i = 0; i < nb; ++i) { int t = bsum[i]; bsum[i] = run; run += t; }
    }
}

__global__ __launch_bounds__(1024)
void scan_c(int* __restrict__ rowstart, const int* __restrict__ bsum, int* __restrict__ cursor) {
    int gid = blockIdx.x * 1024 + threadIdx.x;
    if (gid < N_NODES) {
        int v = rowstart[gid] + bsum[blockIdx.x];
        rowstart[gid] = v;
        cursor[gid] = v;
    }
    if (gid == 0) rowstart[N_NODES] = N_EDGES;
}

// dst-range-binned permute: elist entry = (src*576 + rel*64) | (rel<<26)
__global__ void permute_binned(const int* __restrict__ src, const int* __restrict__ dst,
                               const int* __restrict__ et, int* __restrict__ cursor,
                               unsigned int* __restrict__ elist, int lo, int hi) {
    int e = blockIdx.x * 256 + threadIdx.x;
    if (e < N_EDGES) {
        int d = dst[e];
        if (d >= lo && d < hi) {
            int r = et[e];
            int pos = atomicAdd(&cursor[d], 1);
            elist[pos] = (unsigned int)(src[e] * WCOLS + r * 64) | ((unsigned int)r << 26);
        }
    }
}

// per-edge weight fill: welist[i] = rdeg[rel(elist[i]) * N + dst-node-of-row]
__global__ __launch_bounds__(256)
void wfill_kernel(const unsigned int* __restrict__ elist, const int* __restrict__ rowstart,
                  const float* __restrict__ rdeg, float* __restrict__ welist) {
    const int wave = threadIdx.x >> 6, lane = threadIdx.x & 63;
    const int n = blockIdx.x * 4 + wave;
    const int beg = rowstart[n], end = rowstart[n + 1];
    // 8 per-relation weights for this node
    float w[8];
#pragma unroll
    for (int r = 0; r < 8; ++r) w[r] = rdeg[r * N_NODES + n];
    for (int i = beg + lane; i < end; i += 64) {
        int r = (int)(elist[i] >> 26);
        welist[i] = w[r];
    }
}

// ---------------- GEMM: Out[N][576] (bf16) = A[N][K] @ Wcat ------------------
template <int K, bool AF32>
__global__ __launch_bounds__(256)
void gemm_rows(const void* __restrict__ Araw,
               const unsigned short* __restrict__ BT,
               unsigned short* __restrict__ Out, int nrows) {
    constexpr int KSTEPS = K / 32;
    constexpr int LDB = K + 8;
    __shared__ __align__(16) unsigned short Blds[64 * LDB];
    __shared__ __align__(16) unsigned short stage[4][16 * 64];

    const int wave = threadIdx.x >> 6;
    const int lane = threadIdx.x & 63;
    const int l15 = lane & 15, quad = lane >> 4;
    const int rowbase = blockIdx.x * 64 + wave * 16;
    int arow = rowbase + l15;
    if (arow >= nrows) arow = nrows - 1;

    short8 afrag[KSTEPS];
    if constexpr (AF32) {
        const float* Af = (const float*)Araw;
#pragma unroll
        for (int ks = 0; ks < KSTEPS; ++ks) {
            const float* p = Af + (size_t)arow * K + ks * 32 + quad * 8;
            float4v u0 = *(const float4v*)p;
            float4v u1 = *(const float4v*)(p + 4);
            short8 f;
            f[0] = (short)f2bf(u0[0]); f[1] = (short)f2bf(u0[1]);
            f[2] = (short)f2bf(u0[2]); f[3] = (short)f2bf(u0[3]);
            f[4] = (short)f2bf(u1[0]); f[5] = (short)f2bf(u1[1]);
            f[6] = (short)f2bf(u1[2]); f[7] = (short)f2bf(u1[3]);
            afrag[ks] = f;
        }
    } else {
        const unsigned short* Ab = (const unsigned short*)Araw;
#pragma unroll
        for (int ks = 0; ks < KSTEPS; ++ks)
            afrag[ks] = *(const short8*)(Ab + (size_t)arow * K + ks * 32 + quad * 8);
    }

    for (int chunk = 0; chunk < 9; ++chunk) {
        __syncthreads();
        {
            const unsigned short* src = BT + (size_t)chunk * 64 * K;
            const int nvec = 64 * K / 8;
            for (int i = threadIdx.x; i < nvec; i += 256) {
                int r = i / (K / 8);
                int cpos = (i % (K / 8)) * 8;
                *(uint4*)(&Blds[r * LDB + cpos]) = *(const uint4*)(src + r * K + cpos);
            }
        }
        __syncthreads();

        float4v acc[4];
#pragma unroll
        for (int ct = 0; ct < 4; ++ct) { acc[ct][0] = 0.f; acc[ct][1] = 0.f; acc[ct][2] = 0.f; acc[ct][3] = 0.f; }

#pragma unroll
        for (int ct = 0; ct < 4; ++ct) {
#pragma unroll
            for (int ks = 0; ks < KSTEPS; ++ks) {
                short8 bfrag = *(const short8*)(&Blds[(ct * 16 + l15) * LDB + ks * 32 + quad * 8]);
                acc[ct] = __builtin_amdgcn_mfma_f32_16x16x32_bf16(afrag[ks], bfrag, acc[ct], 0, 0, 0);
            }
        }

#pragma unroll
        for (int ct = 0; ct < 4; ++ct)
#pragma unroll
            for (int r = 0; r < 4; ++r)
                stage[wave][(quad * 4 + r) * 64 + ct * 16 + l15] = f2bf(acc[ct][r]);
        __syncthreads();

        {
            int r = lane >> 2, j = lane & 3;
            int orow = rowbase + r;
            if (orow < nrows) {
#pragma unroll
                for (int p = 0; p < 2; ++p) {
                    int c0 = (j + p * 4) * 8;
                    uint4 v = *(const uint4*)&stage[wave][r * 64 + c0];
                    *(uint4*)(Out + (size_t)orow * WCOLS + chunk * 64 + c0) = v;
                }
            }
        }
    }
}

// ---------------- fused CSR aggregate + root + bias (+relu) ------------------
// one wave per node, lane = channel. 16-deep explicit gather pipeline.
template <int MODE>   // 0: relu -> bf16 h ; 1: -> f32 out
__global__ __launch_bounds__(256)
void agg_fused(const unsigned short* __restrict__ XW,
               const unsigned int* __restrict__ elist,
               const float* __restrict__ welist,
               const int* __restrict__ rowstart,
               const float* __restrict__ bias,
               void* __restrict__ outp) {
    const int wave = threadIdx.x >> 6, lane = threadIdx.x & 63;
    const int n = blockIdx.x * 4 + wave;          // grid covers N exactly
    const int beg = rowstart[n], end = rowstart[n + 1];

    const unsigned short* XWl = XW + lane;        // fold lane offset into base

    float acc = 0.f;
    int i = beg;
    while (i < end) {
        int m = end - i; if (m > 64) m = 64;
        int idx = i + lane; if (idx >= end) idx = end - 1;
        unsigned int ub = elist[idx];             // one coalesced load / 64 edges
        float        wb = welist[idx];

        int j = 0;
        for (; j + 16 <= m; j += 16) {
            float vv[16], ww[16];
#pragma unroll
            for (int t = 0; t < 16; ++t) {
                unsigned int u = (unsigned int)__builtin_amdgcn_readlane((int)ub, j + t) & OFFMASK;
                ww[t] = rl_f(wb, j + t);
                vv[t] = bf2f(XWl[u]);
            }
#pragma unroll
            for (int t = 0; t < 16; ++t) acc += ww[t] * vv[t];
        }
        for (; j + 4 <= m; j += 4) {
            float vv[4], ww[4];
#pragma unroll
            for (int t = 0; t < 4; ++t) {
                unsigned int u = (unsigned int)__builtin_amdgcn_readlane((int)ub, j + t) & OFFMASK;
                ww[t] = rl_f(wb, j + t);
                vv[t] = bf2f(XWl[u]);
            }
#pragma unroll
            for (int t = 0; t < 4; ++t) acc += ww[t] * vv[t];
        }
        for (; j < m; ++j) {
            unsigned int u = (unsigned int)__builtin_amdgcn_readlane((int)ub, j) & OFFMASK;
            float w = rl_f(wb, j);
            acc += w * bf2f(XWl[u]);
        }
        i += m;
    }

    float res = acc + bf2f(XW[(size_t)n * WCOLS + 512 + lane]) + bias[lane];
    if (MODE == 0) {
        res = res > 0.f ? res : 0.f;
        ((unsigned short*)outp)[(size_t)n * 64 + lane] = f2bf(res);
    } else {
        ((float*)outp)[(size_t)n * 64 + lane] = res;
    }
}

// ---------------- launch ------------------------------------------------------
extern "C" void kernel_launch(void* const* d_in, const int* in_sizes, int n_in,
                              void* d_out, int out_size, void* d_ws, size_t ws_size,
                              hipStream_t stream) {
    const float* x     = (const float*)d_in[0];
    const int*   eidx  = (const int*)d_in[1];
    const int*   etyp  = (const int*)d_in[2];
    const float* W1    = (const float*)d_in[3];
    const float* root1 = (const float*)d_in[4];
    const float* b1    = (const float*)d_in[5];
    const float* W2    = (const float*)d_in[6];
    const float* root2 = (const float*)d_in[7];
    const float* b2    = (const float*)d_in[8];
    float*       out   = (float*)d_out;

    char* ws = (char*)d_ws;
    size_t off = 0;
    auto alloc = [&](size_t bytes) { char* p = ws + off; off += (bytes + 255) & ~(size_t)255; return p; };

    unsigned short* xW       = (unsigned short*)alloc((size_t)N_NODES * WCOLS * 2);  // 115.2 MB (reused as hW)
    unsigned short* h        = (unsigned short*)alloc((size_t)N_NODES * HID * 2);    //  12.8 MB
    unsigned int*   elist    = (unsigned int*)alloc((size_t)N_EDGES * 4);            //  12.8 MB
    float*          welist   = (float*)alloc((size_t)N_EDGES * 4);                   //  12.8 MB
    int*            rowstart = (int*)alloc((size_t)(N_NODES + 1) * 4);
    int*            cnt2     = (int*)alloc((size_t)R_REL * N_NODES * 4);             //   3.2 MB
    float*          rdeg     = (float*)alloc((size_t)R_REL * N_NODES * 4);           //   3.2 MB
    int*            cursor   = (int*)alloc((size_t)N_NODES * 4);
    int*            bsum     = (int*)alloc(128 * 4);
    unsigned short* BT1      = (unsigned short*)alloc((size_t)WCOLS * C_IN * 2);
    unsigned short* BT2      = (unsigned short*)alloc((size_t)WCOLS * HID * 2);
    // total ~161 MB

    const int* srcp = eidx;
    const int* dstp = eidx + N_EDGES;

    const int NB_SCAN = (N_NODES + 1023) / 1024;   // 98
    const int eg = (N_EDGES + 255) / 256;          // 12500

    hipMemsetAsync(cnt2, 0, (size_t)R_REL * N_NODES * 4, stream);
    prep_wcat<<<(WCOLS * (C_IN + HID) + 255) / 256, 256, 0, stream>>>(W1, root1, W2, root2, BT1, BT2);

    // CSR build (shared by both layers)
    hist2_kernel<<<eg, 256, 0, stream>>>(dstp, etyp, cnt2);
    recip_kernel<<<(R_REL * N_NODES + 255) / 256, 256, 0, stream>>>(cnt2, rdeg);
    scan_a<<<NB_SCAN, 1024, 0, stream>>>(cnt2, rowstart, bsum);
    scan_b<<<1, 64, 0, stream>>>(bsum, NB_SCAN);
    scan_c<<<NB_SCAN, 1024, 0, stream>>>(rowstart, bsum, cursor);
    for (int p = 0; p < 4; ++p)
        permute_binned<<<eg, 256, 0, stream>>>(srcp, dstp, etyp, cursor, elist,
                                               p * (N_NODES / 4), (p + 1) * (N_NODES / 4));

    const int gemm_grid = (N_NODES + 63) / 64;     // 1563
    const int agg_grid  = N_NODES / 4;             // 25000

    wfill_kernel<<<agg_grid, 256, 0, stream>>>(elist, rowstart, rdeg, welist);

    // layer 1: x (f32) -> xW (bf16) -> h (bf16, relu)
    gemm_rows<C_IN, true><<<gemm_grid, 256, 0, stream>>>((const void*)x, BT1, xW, N_NODES);
    agg_fused<0><<<agg_grid, 256, 0, stream>>>(xW, elist, welist, rowstart, b1, (void*)h);

    // layer 2: h -> hW (reuse xW) -> out (f32)
    gemm_rows<HID, false><<<gemm_grid, 256, 0, stream>>>((const void*)h, BT2, xW, N_NODES);
    agg_fused<1><<<agg_grid, 256, 0, stream>>>(xW, elist, welist, rowstart, b2, (void*)out);
}

// Round 6
// 489.818 us; speedup vs baseline: 3.5850x; 1.3622x over previous
//
#include <hip/hip_runtime.h>

#define N_NODES 100000
#define N_EDGES 3200000
#define R_REL   8
#define C_IN    128
#define HID     64
#define WCOLS   576   // 8 relations * 64 + 64 (root slot)
#define OFFMASK 0x03FFFFFFu

// counting-sort CSR parameters
#define NBUCK 500     // dst buckets
#define NPB   200     // nodes per bucket (500*200 = N)
#define NBLK  1024    // edge chunks
#define CHUNK 3125    // E / NBLK (exact)
#define NCELL (NBUCK * NBLK)   // 512000

typedef __attribute__((ext_vector_type(8))) short  short8;
typedef __attribute__((ext_vector_type(4))) float  float4v;

__device__ __forceinline__ float bf2f(unsigned short u) {
    union { unsigned int i; float f; } v; v.i = ((unsigned int)u) << 16; return v.f;
}
__device__ __forceinline__ unsigned short f2bf(float f) {
    union { float f; unsigned int i; } v; v.f = f;
    unsigned int r = v.i + 0x7FFFu + ((v.i >> 16) & 1u);   // RNE
    return (unsigned short)(r >> 16);
}
__device__ __forceinline__ float rl_f(float v, int j) {
    union { float f; int i; } a, b; a.f = v;
    b.i = __builtin_amdgcn_readlane(a.i, j);
    return b.f;
}

// ---------------- weight prep (f32 -> bf16, concatenated+transposed) ----------
__global__ void prep_wcat(const float* __restrict__ W1,
                          const float* __restrict__ root1,
                          const float* __restrict__ W2,
                          const float* __restrict__ root2,
                          unsigned short* __restrict__ BT1,
                          unsigned short* __restrict__ BT2) {
    int idx = blockIdx.x * 256 + threadIdx.x;
    const int T1 = WCOLS * C_IN;          // 73728
    const int T2 = WCOLS * HID;           // 36864
    if (idx < T1) {
        int c = idx / C_IN, k = idx % C_IN;
        float v;
        if (c < 512) { int r = c >> 6, h = c & 63; v = W1[r * (C_IN * 64) + k * 64 + h]; }
        else         { v = root1[k * 64 + (c - 512)]; }
        BT1[idx] = f2bf(v);
    } else if (idx < T1 + T2) {
        int j = idx - T1;
        int c = j / HID, k = j % HID;
        float v;
        if (c < 512) { int r = c >> 6, h = c & 63; v = W2[r * (HID * 64) + k * 64 + h]; }
        else         { v = root2[k * 64 + (c - 512)]; }
        BT2[j] = f2bf(v);
    }
}

// ---------------- CSR build: LDS counting sort (no global atomics) -----------
// Phase A: per-(bucket, block) edge counts via LDS histogram
__global__ __launch_bounds__(256)
void bucket_count(const int* __restrict__ dst, int* __restrict__ bcount) {
    __shared__ int cnt[NBUCK];
    for (int i = threadIdx.x; i < NBUCK; i += 256) cnt[i] = 0;
    __syncthreads();
    const int e0 = blockIdx.x * CHUNK;
    for (int i = e0 + threadIdx.x; i < e0 + CHUNK; i += 256)
        atomicAdd(&cnt[dst[i] / NPB], 1);
    __syncthreads();
    for (int b = threadIdx.x; b < NBUCK; b += 256)
        bcount[b * NBLK + blockIdx.x] = cnt[b];
}

// exclusive scan over NCELL cells: scan1 (per-block) -> scan2 (block sums) -> scan3 (add)
__global__ __launch_bounds__(1024)
void scan1(const int* __restrict__ in, int* __restrict__ out, int* __restrict__ bsum) {
    __shared__ int tmp[1024];
    int tid = threadIdx.x, gid = blockIdx.x * 1024 + tid;
    int v = (gid < NCELL) ? in[gid] : 0;
    tmp[tid] = v; __syncthreads();
    for (int off = 1; off < 1024; off <<= 1) {
        int t = (tid >= off) ? tmp[tid - off] : 0;
        __syncthreads(); tmp[tid] += t; __syncthreads();
    }
    if (gid < NCELL) out[gid] = tmp[tid] - v;
    if (tid == 1023) bsum[blockIdx.x] = tmp[tid];
}

__global__ __launch_bounds__(512)
void scan2(int* __restrict__ bsum, int nb) {      // nb <= 512
    __shared__ int tmp[512];
    int tid = threadIdx.x;
    int v = (tid < nb) ? bsum[tid] : 0;
    tmp[tid] = v; __syncthreads();
    for (int off = 1; off < 512; off <<= 1) {
        int t = (tid >= off) ? tmp[tid - off] : 0;
        __syncthreads(); tmp[tid] += t; __syncthreads();
    }
    if (tid < nb) bsum[tid] = tmp[tid] - v;       // exclusive
}

__global__ __launch_bounds__(1024)
void scan3(int* __restrict__ out, const int* __restrict__ bsum) {
    int gid = blockIdx.x * 1024 + threadIdx.x;
    if (gid < NCELL) out[gid] += bsum[blockIdx.x];
}

// Phase C: scatter edges into bucket-grouped ebucket via LDS cursors
__global__ __launch_bounds__(256)
void bucket_scatter(const int* __restrict__ src, const int* __restrict__ dst,
                    const int* __restrict__ et, const int* __restrict__ cellstart,
                    unsigned int* __restrict__ ebucket) {
    __shared__ int cur[NBUCK];
    for (int b = threadIdx.x; b < NBUCK; b += 256)
        cur[b] = cellstart[b * NBLK + blockIdx.x];
    __syncthreads();
    const int e0 = blockIdx.x * CHUNK;
    for (int i = e0 + threadIdx.x; i < e0 + CHUNK; i += 256) {
        int d = dst[i];
        int b = d / NPB;
        int pos = atomicAdd(&cur[b], 1);
        ebucket[pos] = ((unsigned int)src[i] << 11) |
                       ((unsigned int)(d - b * NPB) << 3) | (unsigned int)et[i];
    }
}

// Phase D: per-bucket exact CSR: count per (dstLocal, rel), LDS scan, emit
// elist (=src*576+rel*64), welist (=1/deg), rowstart
__global__ __launch_bounds__(256)
void bucket_csr(const unsigned int* __restrict__ ebucket, const int* __restrict__ cellstart,
                unsigned int* __restrict__ elist, float* __restrict__ welist,
                int* __restrict__ rowstart) {
    __shared__ int   cnt[1792];      // (dstLocal*8 + rel), padded to 256*7
    __shared__ int   cur[1792];
    __shared__ float wt[1600];
    __shared__ int   tsum[256];
    const int b = blockIdx.x, tid = threadIdx.x;
    const int seg0 = cellstart[b * NBLK];
    const int seg1 = (b == NBUCK - 1) ? N_EDGES : cellstart[(b + 1) * NBLK];

    for (int i = tid; i < 1792; i += 256) cnt[i] = 0;
    __syncthreads();
    for (int i = seg0 + tid; i < seg1; i += 256) {
        unsigned int e = ebucket[i];
        atomicAdd(&cnt[(int)((e >> 3) & 255u) * 8 + (int)(e & 7u)], 1);
    }
    __syncthreads();

    // exclusive scan over 1792 counters: 7 per thread + Hillis-Steele over 256
    int base = tid * 7, s = 0, loc[7];
#pragma unroll
    for (int k = 0; k < 7; ++k) { loc[k] = s; s += cnt[base + k]; }
    tsum[tid] = s; __syncthreads();
    for (int off = 1; off < 256; off <<= 1) {
        int t = (tid >= off) ? tsum[tid - off] : 0;
        __syncthreads(); tsum[tid] += t; __syncthreads();
    }
    int texcl = tsum[tid] - s;
#pragma unroll
    for (int k = 0; k < 7; ++k) cur[base + k] = texcl + loc[k];
    __syncthreads();

    for (int j = tid; j < 1600; j += 256) {
        int c = cnt[j];
        wt[j] = 1.0f / (float)(c > 1 ? c : 1);
    }
    if (tid < NPB) rowstart[b * NPB + tid] = seg0 + cur[tid * 8];
    if (b == NBUCK - 1 && tid == 0) rowstart[N_NODES] = N_EDGES;
    __syncthreads();

    for (int i = seg0 + tid; i < seg1; i += 256) {
        unsigned int e = ebucket[i];
        int r = (int)(e & 7u);
        int j = (int)((e >> 3) & 255u) * 8 + r;
        int p = atomicAdd(&cur[j], 1);
        elist[seg0 + p]  = (e >> 11) * WCOLS + (unsigned int)(r * 64);
        welist[seg0 + p] = wt[j];
    }
}

// ---------------- GEMM: Out[N][576] (bf16) = A[N][K] @ Wcat ------------------
template <int K, bool AF32>
__global__ __launch_bounds__(256)
void gemm_rows(const void* __restrict__ Araw,
               const unsigned short* __restrict__ BT,
               unsigned short* __restrict__ Out, int nrows) {
    constexpr int KSTEPS = K / 32;
    constexpr int LDB = K + 8;
    __shared__ __align__(16) unsigned short Blds[64 * LDB];
    __shared__ __align__(16) unsigned short stage[4][16 * 64];

    const int wave = threadIdx.x >> 6;
    const int lane = threadIdx.x & 63;
    const int l15 = lane & 15, quad = lane >> 4;
    const int rowbase = blockIdx.x * 64 + wave * 16;
    int arow = rowbase + l15;
    if (arow >= nrows) arow = nrows - 1;

    short8 afrag[KSTEPS];
    if constexpr (AF32) {
        const float* Af = (const float*)Araw;
#pragma unroll
        for (int ks = 0; ks < KSTEPS; ++ks) {
            const float* p = Af + (size_t)arow * K + ks * 32 + quad * 8;
            float4v u0 = *(const float4v*)p;
            float4v u1 = *(const float4v*)(p + 4);
            short8 f;
            f[0] = (short)f2bf(u0[0]); f[1] = (short)f2bf(u0[1]);
            f[2] = (short)f2bf(u0[2]); f[3] = (short)f2bf(u0[3]);
            f[4] = (short)f2bf(u1[0]); f[5] = (short)f2bf(u1[1]);
            f[6] = (short)f2bf(u1[2]); f[7] = (short)f2bf(u1[3]);
            afrag[ks] = f;
        }
    } else {
        const unsigned short* Ab = (const unsigned short*)Araw;
#pragma unroll
        for (int ks = 0; ks < KSTEPS; ++ks)
            afrag[ks] = *(const short8*)(Ab + (size_t)arow * K + ks * 32 + quad * 8);
    }

    for (int chunk = 0; chunk < 9; ++chunk) {
        __syncthreads();
        {
            const unsigned short* src = BT + (size_t)chunk * 64 * K;
            const int nvec = 64 * K / 8;
            for (int i = threadIdx.x; i < nvec; i += 256) {
                int r = i / (K / 8);
                int cpos = (i % (K / 8)) * 8;
                *(uint4*)(&Blds[r * LDB + cpos]) = *(const uint4*)(src + r * K + cpos);
            }
        }
        __syncthreads();

        float4v acc[4];
#pragma unroll
        for (int ct = 0; ct < 4; ++ct) { acc[ct][0] = 0.f; acc[ct][1] = 0.f; acc[ct][2] = 0.f; acc[ct][3] = 0.f; }

#pragma unroll
        for (int ct = 0; ct < 4; ++ct) {
#pragma unroll
            for (int ks = 0; ks < KSTEPS; ++ks) {
                short8 bfrag = *(const short8*)(&Blds[(ct * 16 + l15) * LDB + ks * 32 + quad * 8]);
                acc[ct] = __builtin_amdgcn_mfma_f32_16x16x32_bf16(afrag[ks], bfrag, acc[ct], 0, 0, 0);
            }
        }

#pragma unroll
        for (int ct = 0; ct < 4; ++ct)
#pragma unroll
            for (int r = 0; r < 4; ++r)
                stage[wave][(quad * 4 + r) * 64 + ct * 16 + l15] = f2bf(acc[ct][r]);
        __syncthreads();

        {
            int r = lane >> 2, j = lane & 3;
            int orow = rowbase + r;
            if (orow < nrows) {
#pragma unroll
                for (int p = 0; p < 2; ++p) {
                    int c0 = (j + p * 4) * 8;
                    uint4 v = *(const uint4*)&stage[wave][r * 64 + c0];
                    *(uint4*)(Out + (size_t)orow * WCOLS + chunk * 64 + c0) = v;
                }
            }
        }
    }
}

// ---------------- fused CSR aggregate + root + bias (+relu) ------------------
// one wave per node, lane = channel. 16-deep explicit gather pipeline.
template <int MODE>   // 0: relu -> bf16 h ; 1: -> f32 out
__global__ __launch_bounds__(256)
void agg_fused(const unsigned short* __restrict__ XW,
               const unsigned int* __restrict__ elist,
               const float* __restrict__ welist,
               const int* __restrict__ rowstart,
               const float* __restrict__ bias,
               void* __restrict__ outp) {
    const int wave = threadIdx.x >> 6, lane = threadIdx.x & 63;
    const int n = blockIdx.x * 4 + wave;          // grid covers N exactly
    const int beg = rowstart[n], end = rowstart[n + 1];

    const unsigned short* XWl = XW + lane;        // fold lane offset into base

    float acc = 0.f;
    int i = beg;
    while (i < end) {
        int m = end - i; if (m > 64) m = 64;
        int idx = i + lane; if (idx >= end) idx = end - 1;
        unsigned int ub = elist[idx];             // one coalesced load / 64 edges
        float        wb = welist[idx];

        int j = 0;
        for (; j + 16 <= m; j += 16) {
            float vv[16], ww[16];
#pragma unroll
            for (int t = 0; t < 16; ++t) {
                unsigned int u = (unsigned int)__builtin_amdgcn_readlane((int)ub, j + t) & OFFMASK;
                ww[t] = rl_f(wb, j + t);
                vv[t] = bf2f(XWl[u]);
            }
#pragma unroll
            for (int t = 0; t < 16; ++t) acc += ww[t] * vv[t];
        }
        for (; j + 4 <= m; j += 4) {
            float vv[4], ww[4];
#pragma unroll
            for (int t = 0; t < 4; ++t) {
                unsigned int u = (unsigned int)__builtin_amdgcn_readlane((int)ub, j + t) & OFFMASK;
                ww[t] = rl_f(wb, j + t);
                vv[t] = bf2f(XWl[u]);
            }
#pragma unroll
            for (int t = 0; t < 4; ++t) acc += ww[t] * vv[t];
        }
        for (; j < m; ++j) {
            unsigned int u = (unsigned int)__builtin_amdgcn_readlane((int)ub, j) & OFFMASK;
            float w = rl_f(wb, j);
            acc += w * bf2f(XWl[u]);
        }
        i += m;
    }

    float res = acc + bf2f(XW[(size_t)n * WCOLS + 512 + lane]) + bias[lane];
    if (MODE == 0) {
        res = res > 0.f ? res : 0.f;
        ((unsigned short*)outp)[(size_t)n * 64 + lane] = f2bf(res);
    } else {
        ((float*)outp)[(size_t)n * 64 + lane] = res;
    }
}

// ---------------- launch ------------------------------------------------------
extern "C" void kernel_launch(void* const* d_in, const int* in_sizes, int n_in,
                              void* d_out, int out_size, void* d_ws, size_t ws_size,
                              hipStream_t stream) {
    const float* x     = (const float*)d_in[0];
    const int*   eidx  = (const int*)d_in[1];
    const int*   etyp  = (const int*)d_in[2];
    const float* W1    = (const float*)d_in[3];
    const float* root1 = (const float*)d_in[4];
    const float* b1    = (const float*)d_in[5];
    const float* W2    = (const float*)d_in[6];
    const float* root2 = (const float*)d_in[7];
    const float* b2    = (const float*)d_in[8];
    float*       out   = (float*)d_out;

    char* ws = (char*)d_ws;
    size_t off = 0;
    auto alloc = [&](size_t bytes) { char* p = ws + off; off += (bytes + 255) & ~(size_t)255; return p; };

    unsigned short* xW       = (unsigned short*)alloc((size_t)N_NODES * WCOLS * 2);  // 115.2 MB (reused as hW)
    unsigned short* h        = (unsigned short*)alloc((size_t)N_NODES * HID * 2);    //  12.8 MB
    unsigned int*   elist    = (unsigned int*)alloc((size_t)N_EDGES * 4);            //  12.8 MB
    float*          welist   = (float*)alloc((size_t)N_EDGES * 4);                   //  12.8 MB
    int*            rowstart = (int*)alloc((size_t)(N_NODES + 1) * 4);
    unsigned short* BT1      = (unsigned short*)alloc((size_t)WCOLS * C_IN * 2);
    unsigned short* BT2      = (unsigned short*)alloc((size_t)WCOLS * HID * 2);
    // total ~154 MB

    // CSR scratch aliases into xW (only live before gemm1)
    unsigned int* ebucket   = (unsigned int*)xW;                         // 12.8 MB
    int*          bcount    = (int*)((char*)xW + (size_t)N_EDGES * 4);   //  2.05 MB
    int*          cellstart = bcount + NCELL;                            //  2.05 MB
    int*          bsum      = cellstart + NCELL;                         //  2 KB

    const int* srcp = eidx;
    const int* dstp = eidx + N_EDGES;

    prep_wcat<<<(WCOLS * (C_IN + HID) + 255) / 256, 256, 0, stream>>>(W1, root1, W2, root2, BT1, BT2);

    // CSR build — LDS counting sort, no global atomics
    bucket_count<<<NBLK, 256, 0, stream>>>(dstp, bcount);
    scan1<<<(NCELL + 1023) / 1024, 1024, 0, stream>>>(bcount, cellstart, bsum);   // 500 blocks
    scan2<<<1, 512, 0, stream>>>(bsum, (NCELL + 1023) / 1024);
    scan3<<<(NCELL + 1023) / 1024, 1024, 0, stream>>>(cellstart, bsum);
    bucket_scatter<<<NBLK, 256, 0, stream>>>(srcp, dstp, etyp, cellstart, ebucket);
    bucket_csr<<<NBUCK, 256, 0, stream>>>(ebucket, cellstart, elist, welist, rowstart);

    const int gemm_grid = (N_NODES + 63) / 64;     // 1563
    const int agg_grid  = N_NODES / 4;             // 25000

    // layer 1: x (f32) -> xW (bf16) -> h (bf16, relu)
    gemm_rows<C_IN, true><<<gemm_grid, 256, 0, stream>>>((const void*)x, BT1, xW, N_NODES);
    agg_fused<0><<<agg_grid, 256, 0, stream>>>(xW, elist, welist, rowstart, b1, (void*)h);

    // layer 2: h -> hW (reuse xW) -> out (f32)
    gemm_rows<HID, false><<<gemm_grid, 256, 0, stream>>>((const void*)h, BT2, xW, N_NODES);
    agg_fused<1><<<agg_grid, 256, 0, stream>>>(xW, elist, welist, rowstart, b2, (void*)out);
}